// Round 11
// baseline (659.122 us; speedup 1.0000x reference)
//
#include <hip/hip_runtime.h>

// ---------------------------------------------------------------------------
// HeteroTripartiteGCN, round 10 (resubmit — r10 bench hit GPU acquisition
// timeout, no data): fused finesort+gather (block-local dep).
//   1) fused transforms (fp32 -> bf16 tables)
//   2) bucketize_cm: block per 16K-edge chunk, chunk-major bucket-grouped
//      records + run directory + bucket totals (r9, unchanged)
//   3) sortgather: block per bucket.
//        a) inline prefix over bucketTotal -> arena base s (no bscan kernel)
//        b) count (row_local, rel) over the bucket's runs -> LDS scan
//        c) scatter packed 4B entries into bucket's arena segment (L2-hot)
//        d) gather phase IN THE SAME BLOCK: wave per row, half-wave per
//           edge, bf16 features, fused ReLU store. Arena is L2-hot, rowptr
//           lives in LDS (never materialized globally).
// d_out: [msg_u | msg_v | msg_f] fp32, every row written exactly once.
// ---------------------------------------------------------------------------

#define TDIM 64
#define EPB  16384

struct Rel {
    const int* rows; const int* cols; const float* vals;
    int n, chunk0, boff, shift, srcflag, eoff;
};
struct RelPack { Rel r[6]; };

struct TPack {
    const float* X[3]; const float* W1[3]; const float* W2[3];
    unsigned short* Y1[3]; unsigned short* Y2[3];
    int N[3]; int c0[3];
};

struct SGPack {
    const unsigned* srcA[3]; const unsigned* srcB[3];
    int c0A[3], cntA[3], offA[3];
    int c0B[3], cntB[3], offB[3];
};

__device__ __forceinline__ unsigned short f2bf(float f) {
    union { float f; unsigned u; } c; c.f = f;
    unsigned r = c.u + 0x7FFFu + ((c.u >> 16) & 1u);  // RNE
    return (unsigned short)(r >> 16);
}
__device__ __forceinline__ float bflo(unsigned x) { return __uint_as_float(x << 16); }
__device__ __forceinline__ float bfhi(unsigned x) { return __uint_as_float(x & 0xFFFF0000u); }
__device__ __forceinline__ float pval(unsigned p) {
    return __uint_as_float((p & 0x7FFFu) << 16);     // bf16 val, sign==0
}

// ---------------- fused dense transforms (fp32 in, bf16 out) ----------------
__global__ __launch_bounds__(256) void transform_fused_kernel(TPack T)
{
    __shared__ float xsT[64 * 68];
    __shared__ float w1s[64 * 64];
    __shared__ float w2s[64 * 64];

    int t = 0;
    if ((int)blockIdx.x >= T.c0[1]) t = 1;
    if ((int)blockIdx.x >= T.c0[2]) t = 2;
    const float* __restrict__ X  = T.X[t];
    const float* __restrict__ W1 = T.W1[t];
    const float* __restrict__ W2 = T.W2[t];
    unsigned short* __restrict__ Y1 = T.Y1[t];
    unsigned short* __restrict__ Y2 = T.Y2[t];
    const int N    = T.N[t];
    const int row0 = (blockIdx.x - T.c0[t]) * 64;
    const int tid  = threadIdx.x;

    for (int i = tid * 4; i < 4096; i += 256 * 4) {
        *(float4*)&w1s[i] = *(const float4*)&W1[i];
        *(float4*)&w2s[i] = *(const float4*)&W2[i];
    }
    {
        const int r  = tid >> 2;
        const int c0 = (tid & 3) * 16;
        const int gr = row0 + r;
        #pragma unroll
        for (int cc = 0; cc < 16; cc += 4) {
            const int c = c0 + cc;
            float4 v = make_float4(0.f, 0.f, 0.f, 0.f);
            if (gr < N) v = *(const float4*)&X[(size_t)gr * TDIM + c];
            xsT[(c + 0) * 68 + r] = v.x;
            xsT[(c + 1) * 68 + r] = v.y;
            xsT[(c + 2) * 68 + r] = v.z;
            xsT[(c + 3) * 68 + r] = v.w;
        }
    }
    __syncthreads();

    const int tx = tid & 15;
    const int ty = tid >> 4;
    float a1[4][4] = {{0.f}}, a2[4][4] = {{0.f}};

    #pragma unroll 8
    for (int k = 0; k < 64; ++k) {
        const float4 xv = *(const float4*)&xsT[k * 68 + ty * 4];
        const float4 w1 = *(const float4*)&w1s[k * 64 + tx * 4];
        const float4 w2 = *(const float4*)&w2s[k * 64 + tx * 4];
        const float xr[4] = {xv.x, xv.y, xv.z, xv.w};
        const float c1[4] = {w1.x, w1.y, w1.z, w1.w};
        const float c2[4] = {w2.x, w2.y, w2.z, w2.w};
        #pragma unroll
        for (int r = 0; r < 4; ++r)
            #pragma unroll
            for (int c = 0; c < 4; ++c) {
                a1[r][c] = fmaf(xr[r], c1[c], a1[r][c]);
                a2[r][c] = fmaf(xr[r], c2[c], a2[r][c]);
            }
    }
    #pragma unroll
    for (int r = 0; r < 4; ++r) {
        const int gr = row0 + ty * 4 + r;
        if (gr < N) {
            ushort4 o1, o2;
            o1.x = f2bf(a1[r][0]); o1.y = f2bf(a1[r][1]);
            o1.z = f2bf(a1[r][2]); o1.w = f2bf(a1[r][3]);
            o2.x = f2bf(a2[r][0]); o2.y = f2bf(a2[r][1]);
            o2.z = f2bf(a2[r][2]); o2.w = f2bf(a2[r][3]);
            ((ushort4*)Y1)[(size_t)gr * 16 + tx] = o1;
            ((ushort4*)Y2)[(size_t)gr * 16 + tx] = o2;
        }
    }
}

__device__ __forceinline__ int find_rel(const RelPack& P, int chunk) {
    int ri = 0;
    if (chunk >= P.r[1].chunk0) ri = 1;
    if (chunk >= P.r[2].chunk0) ri = 2;
    if (chunk >= P.r[3].chunk0) ri = 3;
    if (chunk >= P.r[4].chunk0) ri = 4;
    if (chunk >= P.r[5].chunk0) ri = 5;
    return ri;
}

// ---------------- bucketize, chunk-major (r9, unchanged) ----------------
__global__ __launch_bounds__(512) void bucketize_cm_kernel(
    RelPack P, uint2* __restrict__ recs, int* __restrict__ localStart,
    int* __restrict__ bucketTotal, int NB)
{
    __shared__ int cnt[1024];
    __shared__ int sh[512];

    const int tid   = threadIdx.x;
    const int chunk = blockIdx.x;
    for (int t = tid; t < NB; t += 512) cnt[t] = 0;
    __syncthreads();

    const int ri = find_rel(P, chunk);
    const Rel M = P.r[ri];
    const int i0    = (chunk - M.chunk0) * EPB;
    const int rbase = M.eoff + i0;

    #pragma unroll
    for (int k = 0; k < EPB / 512; ++k) {
        const int i = i0 + tid + k * 512;
        if (i < M.n) atomicAdd(&cnt[M.boff + (M.rows[i] >> M.shift)], 1);
    }
    __syncthreads();

    const int i0b = 2 * tid, i1b = 2 * tid + 1;
    const int v0 = (i0b < NB) ? cnt[i0b] : 0;
    const int v1 = (i1b < NB) ? cnt[i1b] : 0;
    if (v0) atomicAdd(&bucketTotal[i0b], v0);
    if (v1) atomicAdd(&bucketTotal[i1b], v1);
    sh[tid] = v0 + v1;
    __syncthreads();
    for (int off = 1; off < 512; off <<= 1) {
        const int x = (tid >= off) ? sh[tid - off] : 0;
        __syncthreads();
        sh[tid] += x;
        __syncthreads();
    }
    const int base0 = tid ? sh[tid - 1] : 0;

    const size_t lb = (size_t)chunk * (NB + 1);
    if (i0b < NB) localStart[lb + i0b] = base0;
    if (i1b < NB) localStart[lb + i1b] = base0 + v0;
    if (i0b == NB)      localStart[lb + NB] = base0;
    else if (i1b == NB) localStart[lb + NB] = base0 + v0;
    if (i0b < NB) cnt[i0b] = base0;
    if (i1b < NB) cnt[i1b] = base0 + v0;
    __syncthreads();

    const unsigned flag = (unsigned)M.srcflag << 31;
    const int mask = (1 << M.shift) - 1;
    #pragma unroll
    for (int k = 0; k < EPB / 512; ++k) {
        const int i = i0 + tid + k * 512;
        if (i < M.n) {
            const int row = M.rows[i];
            const int b   = M.boff + (row >> M.shift);
            const int pos = atomicAdd(&cnt[b], 1);
            uint2 rec;
            rec.x = (unsigned)M.cols[i] | flag;
            rec.y = ((unsigned)(row & mask) << 16) | (unsigned)f2bf(M.vals[i]);
            recs[rbase + pos] = rec;
        }
    }
}

// ---------------- fused finesort + gather: block per bucket ----------------
__global__ __launch_bounds__(512) void sortgather_kernel(
    const uint2* __restrict__ recs, const int* __restrict__ localStart,
    const int* __restrict__ bucketTotal, SGPack F,
    unsigned* __restrict__ arena, float* __restrict__ out,
    int nbU, int nbV, int NU, int NV, int NF, int NB)
{
    __shared__ int startS[513];   // bin starts (local), [0..nbins]
    __shared__ int cur[512];
    __shared__ int sh[512];
    __shared__ int runS[256], runE[256];

    const int b   = blockIdx.x;
    const int tid = threadIdx.x;

    int t, lb, rowbase;
    if (b < nbU)              { t = 0; lb = b;              rowbase = 0; }
    else if (b < nbU + nbV)   { t = 1; lb = b - nbU;        rowbase = NU; }
    else                      { t = 2; lb = b - nbU - nbV;  rowbase = NU + NV; }
    const int shift     = (t == 2) ? 6 : 8;
    const int Ntype     = (t == 0) ? NU : (t == 1) ? NV : NF;
    const int row_start = lb << shift;
    const int nrows     = min(1 << shift, Ntype - row_start);
    const int nbins     = (1 << shift) * 2;
    const int grow0     = rowbase + row_start;

    // ---- inline prefix: s = sum(bucketTotal[0..b)) ----
    int accp = 0;
    for (int i = tid; i < b; i += 512) accp += bucketTotal[i];
    sh[tid] = accp;
    __syncthreads();
    for (int off = 256; off > 0; off >>= 1) {
        if (tid < off) sh[tid] += sh[tid + off];
        __syncthreads();
    }
    const int s = sh[0];
    __syncthreads();

    // ---- run directory ----
    const int nA = F.cntA[t], nB_ = F.cntB[t];
    const int nRuns = nA + nB_;
    if (tid < nRuns) {
        int c, base;
        if (tid < nA) { c = F.c0A[t] + tid; base = F.offA[t] + tid * EPB; }
        else          { int k = tid - nA;
                        c = F.c0B[t] + k;   base = F.offB[t] + k * EPB; }
        const size_t lbi = (size_t)c * (NB + 1) + b;
        runS[tid] = base + localStart[lbi];
        runE[tid] = base + localStart[lbi + 1];
    }
    if (tid < nbins) cur[tid] = 0;
    __syncthreads();

    const int wave = tid >> 6;
    const int lane = tid & 63;

    // ---- count (row_local, rel) ----
    for (int ridx = wave; ridx < nRuns; ridx += 8) {
        const int rs = runS[ridx], re = runE[ridx];
        for (int j = rs + lane; j < re; j += 64) {
            const uint2 r = recs[j];
            const int bin = (int)((r.y >> 16) << 1) | (int)(r.x >> 31);
            atomicAdd(&cur[bin], 1);
        }
    }
    __syncthreads();

    // ---- exclusive scan over nbins (<=512) ----
    const int v = (tid < nbins) ? cur[tid] : 0;
    sh[tid] = v;
    __syncthreads();
    for (int off = 1; off < 512; off <<= 1) {
        const int x = (tid >= off) ? sh[tid - off] : 0;
        __syncthreads();
        sh[tid] += x;
        __syncthreads();
    }
    const int excl = sh[tid] - v;
    if (tid < nbins) { startS[tid] = excl; cur[tid] = excl; }
    if (tid == nbins - 1) startS[nbins] = sh[tid];   // bucket total
    __syncthreads();

    // ---- scatter packed payload into bucket's arena segment (L2-hot) ----
    for (int ridx = wave; ridx < nRuns; ridx += 8) {
        const int rs = runS[ridx], re = runE[ridx];
        for (int j = rs + lane; j < re; j += 64) {
            const uint2 r = recs[j];
            const int bin = (int)((r.y >> 16) << 1) | (int)(r.x >> 31);
            const int pos = s + atomicAdd(&cur[bin], 1);
            arena[pos] = ((r.x & 0x7FFFFFFFu) << 15) | (r.y & 0x7FFFu);
        }
    }
    __syncthreads();

    // ---- gather phase: wave per row, half-wave per edge, fused ReLU ----
    const unsigned* __restrict__ srcA = F.srcA[t];
    const unsigned* __restrict__ srcB = F.srcB[t];
    const int half = lane >> 5;
    const int sub  = lane & 31;

    for (int r = wave; r < nrows; r += 8) {
        const int pa = s + startS[2 * r];
        const int pm = s + startS[2 * r + 1];
        const int pe = s + startS[2 * r + 2];

        float accx = 0.f, accy = 0.f;

        #pragma unroll
        for (int hh = 0; hh < 2; ++hh) {
            const unsigned* __restrict__ src = hh ? srcB : srcA;
            const int ss = hh ? pm : pa;
            const int ee = hh ? pe : pm;
            int j = ss;
            for (; j + 8 <= ee; j += 8) {      // 8 edges: 4 per half-wave
                unsigned cv[4], x[4];
                #pragma unroll
                for (int q = 0; q < 4; ++q) cv[q] = arena[j + 2 * q + half];
                #pragma unroll
                for (int q = 0; q < 4; ++q)
                    x[q] = src[(size_t)(cv[q] >> 15) * 32 + sub];
                #pragma unroll
                for (int q = 0; q < 4; ++q) {
                    const float w = pval(cv[q]);
                    accx = fmaf(w, bflo(x[q]), accx);
                    accy = fmaf(w, bfhi(x[q]), accy);
                }
            }
            for (; j + 2 <= ee; j += 2) {
                const unsigned cv = arena[j + half];
                const unsigned x  = src[(size_t)(cv >> 15) * 32 + sub];
                const float w = pval(cv);
                accx = fmaf(w, bflo(x), accx);
                accy = fmaf(w, bfhi(x), accy);
            }
            if (half == 0 && j < ee) {
                const unsigned cv = arena[j];
                const unsigned x  = src[(size_t)(cv >> 15) * 32 + sub];
                const float w = pval(cv);
                accx = fmaf(w, bflo(x), accx);
                accy = fmaf(w, bfhi(x), accy);
            }
        }

        accx += __shfl_xor(accx, 32, 64);
        accy += __shfl_xor(accy, 32, 64);
        if (half == 0) {
            float2 o = make_float2(fmaxf(accx, 0.f), fmaxf(accy, 0.f));
            ((float2*)out)[(size_t)(grow0 + r) * 32 + sub] = o;
        }
    }
}

// ---------------------------------------------------------------------------
extern "C" void kernel_launch(void* const* d_in, const int* in_sizes, int n_in,
                              void* d_out, int out_size, void* d_ws, size_t ws_size,
                              hipStream_t stream)
{
    const float* x_u    = (const float*)d_in[0];
    const float* x_v    = (const float*)d_in[1];
    const float* x_f    = (const float*)d_in[2];
    const float* W_u_uv = (const float*)d_in[3];
    const float* W_v_uv = (const float*)d_in[4];
    const float* W_f2u  = (const float*)d_in[5];
    const float* W_f2v  = (const float*)d_in[6];
    const float* W_u2f  = (const float*)d_in[7];
    const float* W_v2f  = (const float*)d_in[8];

    const int* rows_[6] = {(const int*)d_in[9],  (const int*)d_in[12],
                           (const int*)d_in[15], (const int*)d_in[18],
                           (const int*)d_in[21], (const int*)d_in[24]};
    const int* cols_[6] = {(const int*)d_in[10], (const int*)d_in[13],
                           (const int*)d_in[16], (const int*)d_in[19],
                           (const int*)d_in[22], (const int*)d_in[25]};
    const float* vals_[6] = {(const float*)d_in[11], (const float*)d_in[14],
                             (const float*)d_in[17], (const float*)d_in[20],
                             (const float*)d_in[23], (const float*)d_in[26]};

    const int NU = in_sizes[0] / TDIM;
    const int NV = in_sizes[1] / TDIM;
    const int NF = in_sizes[2] / TDIM;
    const int E_[6] = {in_sizes[9], in_sizes[12], in_sizes[15],
                       in_sizes[18], in_sizes[21], in_sizes[24]};

    const int nbU = (NU + 255) >> 8;
    const int nbV = (NV + 255) >> 8;
    const int nbF = (NF + 63) >> 6;
    const int NB  = nbU + nbV + nbF;

    // u: rel0 uv (A=tmp_v), rel2 uf (B=f2u)
    // v: rel1 vu (A=tmp_u), rel3 vf (B=f2v)
    // f: rel4 fu (A=u2f),  rel5 fv (B=v2f)
    const int boff_[6]  = {0, nbU, 0, nbU, nbU + nbV, nbU + nbV};
    const int shift_[6] = {8, 8, 8, 8, 6, 6};
    const int sflag_[6] = {0, 0, 1, 1, 0, 1};

    size_t etot = 0;
    int eoff_[6];
    for (int r = 0; r < 6; ++r) { eoff_[r] = (int)etot; etot += (size_t)E_[r]; }

    // ---- relation pack / chunk map ----
    RelPack P;
    int nchunks = 0;
    int relchunks[6];
    for (int r = 0; r < 6; ++r) {
        P.r[r].rows = rows_[r]; P.r[r].cols = cols_[r]; P.r[r].vals = vals_[r];
        P.r[r].n = E_[r]; P.r[r].chunk0 = nchunks;
        P.r[r].boff = boff_[r]; P.r[r].shift = shift_[r]; P.r[r].srcflag = sflag_[r];
        P.r[r].eoff = eoff_[r];
        relchunks[r] = (E_[r] + EPB - 1) / EPB;
        nchunks += relchunks[r];
    }

    // ---- workspace ----
    char* wsb = (char*)d_ws;
    size_t o = 0;
    auto alloc = [&](size_t bytes) {
        char* p = wsb + o;
        o = (o + bytes + 15) & ~(size_t)15;
        return p;
    };
    unsigned short* tmp_u = (unsigned short*)alloc((size_t)NU * TDIM * 2);
    unsigned short* u2f   = (unsigned short*)alloc((size_t)NU * TDIM * 2);
    unsigned short* tmp_v = (unsigned short*)alloc((size_t)NV * TDIM * 2);
    unsigned short* v2f   = (unsigned short*)alloc((size_t)NV * TDIM * 2);
    unsigned short* f2u   = (unsigned short*)alloc((size_t)NF * TDIM * 2);
    unsigned short* f2v   = (unsigned short*)alloc((size_t)NF * TDIM * 2);
    int* localStart  = (int*)alloc((size_t)nchunks * (NB + 1) * 4);
    int* bucketTotal = (int*)alloc((size_t)NB * 4);
    uint2* recs      = (uint2*)alloc(etot * 8);
    unsigned* arena  = (unsigned*)alloc(etot * 4);
    (void)ws_size;

    // ---- fused transforms ----
    TPack T;
    T.X[0] = x_u; T.W1[0] = W_u_uv; T.W2[0] = W_u2f; T.Y1[0] = tmp_u; T.Y2[0] = u2f; T.N[0] = NU;
    T.X[1] = x_v; T.W1[1] = W_v_uv; T.W2[1] = W_v2f; T.Y1[1] = tmp_v; T.Y2[1] = v2f; T.N[1] = NV;
    T.X[2] = x_f; T.W1[2] = W_f2u;  T.W2[2] = W_f2v; T.Y1[2] = f2u;  T.Y2[2] = f2v; T.N[2] = NF;
    T.c0[0] = 0;
    T.c0[1] = (NU + 63) / 64;
    T.c0[2] = T.c0[1] + (NV + 63) / 64;
    const int tchunks = T.c0[2] + (NF + 63) / 64;
    transform_fused_kernel<<<tchunks, 256, 0, stream>>>(T);

    // ---- bucketize ----
    hipMemsetAsync(bucketTotal, 0, (size_t)NB * sizeof(int), stream);
    bucketize_cm_kernel<<<nchunks, 512, 0, stream>>>(P, recs, localStart, bucketTotal, NB);

    // ---- fused sort + gather ----
    SGPack F;
    const int Arel[3] = {0, 1, 4}, Brel[3] = {2, 3, 5};
    F.srcA[0] = (const unsigned*)tmp_v; F.srcB[0] = (const unsigned*)f2u;
    F.srcA[1] = (const unsigned*)tmp_u; F.srcB[1] = (const unsigned*)f2v;
    F.srcA[2] = (const unsigned*)u2f;   F.srcB[2] = (const unsigned*)v2f;
    for (int t = 0; t < 3; ++t) {
        F.c0A[t] = P.r[Arel[t]].chunk0; F.cntA[t] = relchunks[Arel[t]]; F.offA[t] = eoff_[Arel[t]];
        F.c0B[t] = P.r[Brel[t]].chunk0; F.cntB[t] = relchunks[Brel[t]]; F.offB[t] = eoff_[Brel[t]];
    }
    sortgather_kernel<<<NB, 512, 0, stream>>>(
        recs, localStart, bucketTotal, F, arena, (float*)d_out,
        nbU, nbV, NU, NV, NF, NB);
}